// Round 4
// baseline (61471.918 us; speedup 1.0000x reference)
//
#include <hip/hip_runtime.h>

#define Bdim 128
#define Tdim 256
#define Hdim 512
#define INdim 300
#define KXdim 320
#define NC 45
#define NTHR 256

typedef _Float16 h16;
typedef __attribute__((ext_vector_type(8))) _Float16 half8;
typedef __attribute__((ext_vector_type(4))) float float4v;
typedef unsigned long long u64;

__device__ __forceinline__ float fast_tanh(float v) {
    float e = __expf(2.0f * v);
    return 1.0f - 2.0f / (e + 1.0f);
}

// ---- coherence-point (sc0 sc1) helpers: relaxed agent-scope atomics ----
__device__ __forceinline__ int ld_flag(const int* p) {
    return __hip_atomic_load((int*)p, __ATOMIC_RELAXED, __HIP_MEMORY_SCOPE_AGENT);
}
__device__ __forceinline__ void st_flag(int* p, int v) {
    __hip_atomic_store(p, v, __ATOMIC_RELAXED, __HIP_MEMORY_SCOPE_AGENT);
}
__device__ __forceinline__ float ld_f32c(const float* p) {
    return __hip_atomic_load((float*)p, __ATOMIC_RELAXED, __HIP_MEMORY_SCOPE_AGENT);
}
__device__ __forceinline__ void st_f32c(float* p, float v) {
    __hip_atomic_store(p, v, __ATOMIC_RELAXED, __HIP_MEMORY_SCOPE_AGENT);
}
// 16B fragment as two b64 relaxed agent atomics (sc-bypass, pipelined issue)
__device__ __forceinline__ half8 ld16c(const h16* p) {
    union { u64 u[2]; half8 h; } r;
    const u64* q = (const u64*)p;
    r.u[0] = __hip_atomic_load((u64*)(q + 0), __ATOMIC_RELAXED, __HIP_MEMORY_SCOPE_AGENT);
    r.u[1] = __hip_atomic_load((u64*)(q + 1), __ATOMIC_RELAXED, __HIP_MEMORY_SCOPE_AGENT);
    return r.h;
}
__device__ __forceinline__ void st16c(h16* p, const u64* u) {
    u64* q = (u64*)p;
    __hip_atomic_store(q + 0, u[0], __ATOMIC_RELAXED, __HIP_MEMORY_SCOPE_AGENT);
    __hip_atomic_store(q + 1, u[1], __ATOMIC_RELAXED, __HIP_MEMORY_SCOPE_AGENT);
}

// ---------------- prep1: W0 = Wemb @ Wx0 (fp32), cb fused biases ----------------
__global__ __launch_bounds__(NTHR) void prep1_kernel(
    const float* Wemb, const float* bemb,
    const float* Wx_l2r, const float* bx_l2r, const float* bh_l2r,
    const float* Wx_r2l, const float* bx_r2l, const float* bh_r2l,
    float* W0, float* cb)
{
    int gid = blockIdx.x * NTHR + threadIdx.x;
    const int nW0 = 2 * KXdim * Hdim;
    if (gid < nW0) {
        int dir = gid / (KXdim * Hdim);
        int rem = gid % (KXdim * Hdim);
        int i = rem / Hdim, h = rem % Hdim;
        const float* Wx = dir ? Wx_r2l : Wx_l2r;
        float s = 0.f;
        if (i < INdim) {
            for (int k = 0; k < Hdim; ++k)
                s += Wemb[i * Hdim + k] * Wx[k * Hdim + h];
        }
        W0[gid] = s;
    } else {
        int idx = gid - nW0;
        if (idx < 2 * 3 * Hdim) {
            int dir = idx / (3 * Hdim);
            int l = (idx / Hdim) % 3;
            int h = idx % Hdim;
            const float* Wx = dir ? Wx_r2l : Wx_l2r;
            const float* bx = dir ? bx_r2l : bx_l2r;
            const float* bh = dir ? bh_r2l : bh_l2r;
            float s = bx[l * Hdim + h] + bh[l * Hdim + h];
            if (l == 0) {
                for (int k = 0; k < Hdim; ++k)
                    s += bemb[k] * Wx[k * Hdim + h];
            }
            cb[idx] = s;
        }
    }
}

// ---------------- pack_W: fp16 B-frag layout [u][ks32][nt32][lane64][j8] ---------
// ks 0..15 = Wx (k = h_low dim), ks 16..31 = Wh (k = h_prev dim)
__global__ __launch_bounds__(NTHR) void pack_W_kernel(
    const float* W0,
    const float* Wx_l2r, const float* Wh_l2r,
    const float* Wx_r2l, const float* Wh_r2l,
    h16* Wfrag)
{
    int e = blockIdx.x * NTHR + threadIdx.x;
    if (e >= 6 * 32 * 32 * 64 * 8) return;
    int j    = e & 7;
    int lane = (e >> 3) & 63;
    int nt   = (e >> 9) & 31;
    int ks   = (e >> 14) & 31;
    int u    = e >> 19;
    int dir = u / 3, l = u % 3;
    int n  = nt * 16 + (lane & 15);
    int kk = ks * 32 + ((lane >> 4) * 8) + j;    // 0..1023
    float v;
    if (kk < 512) {
        if (l == 0) {
            v = (kk < KXdim) ? W0[(dir * KXdim + kk) * Hdim + n] : 0.f;
        } else {
            const float* Wx = dir ? Wx_r2l : Wx_l2r;
            v = Wx[(l * Hdim + kk) * Hdim + n];
        }
    } else {
        const float* Wh = dir ? Wh_r2l : Wh_l2r;
        v = Wh[(l * Hdim + (kk - 512)) * Hdim + n];
    }
    Wfrag[e] = (h16)v;
}

// ---------------- pack_W0f: fp16 B-frags of W0 for zx0 kernel --------------------
__global__ __launch_bounds__(NTHR) void pack_W0f_kernel(const float* W0, h16* W0f)
{
    int e = blockIdx.x * NTHR + threadIdx.x;
    if (e >= 2 * 32 * 10 * 64 * 8) return;
    int j    = e & 7;
    int lane = (e >> 3) & 63;
    int rest = e >> 9;
    int ks   = rest % 10;
    rest /= 10;
    int nt   = rest & 31;
    int dir  = rest >> 5;
    int k = ks * 32 + ((lane >> 4) * 8) + j;
    int n = nt * 16 + (lane & 15);
    W0f[e] = (h16)W0[(dir * KXdim + k) * Hdim + n];
}

// ---------------- zx0: zx0f[dir][t][nt32][mt8][lane64][reg4] fp16 ----------------
__global__ __launch_bounds__(NTHR) void zx0_kernel(
    const float* __restrict__ x0, const float* __restrict__ x1,
    const h16* __restrict__ W0f, const float* __restrict__ cb,
    h16* __restrict__ zx0f)
{
    int bx = blockIdx.x;
    int t = bx & 255, mh = (bx >> 8) & 1, dir = bx >> 9;
    const int tid = threadIdx.x;
    __shared__ h16 xl[64 * 328];
    const float* xs = dir ? x1 : x0;
    for (int i = tid; i < 64 * 328; i += NTHR) {
        int r = i / 328, k = i - r * 328;
        int b = mh * 64 + r;
        float v = (k < INdim) ? xs[(b * Tdim + t) * INdim + k] : 0.f;
        xl[i] = (h16)v;
    }
    __syncthreads();
    int wave = tid >> 6, lane = tid & 63;
    int r15 = lane & 15, q = lane >> 4;
    for (int nt = 0; nt < 32; ++nt) {
        float4v acc = {0.f, 0.f, 0.f, 0.f};
        #pragma unroll
        for (int ks = 0; ks < 10; ++ks) {
            half8 af = *(const half8*)&xl[(wave * 16 + r15) * 328 + ks * 32 + q * 8];
            half8 bf = *(const half8*)&W0f[(((dir * 32 + nt) * 10 + ks) * 64 + lane) * 8];
            acc = __builtin_amdgcn_mfma_f32_16x16x32_f16(af, bf, acc, 0, 0, 0);
        }
        int col = nt * 16 + r15;
        float cbv = cb[(dir * 3 + 0) * Hdim + col];
        union { h16 h[4]; uint2 u2; } o;
        #pragma unroll
        for (int r = 0; r < 4; ++r) o.h[r] = (h16)(acc[r] + cbv);
        h16* dst = zx0f + (((( (size_t)dir * Tdim + t) * 32 + nt) * 8 + (mh * 4 + wave)) * 64 + lane) * 4;
        *(uint2*)dst = o.u2;
    }
}

// ---------------- zeroinit: hbuf ring slot 7 + flags -----------------------------
__global__ __launch_bounds__(NTHR) void zeroinit_kernel(uint4* hbuf4, int* zdone, int* hdone)
{
    int gid = blockIdx.x * NTHR + threadIdx.x;
    if (gid < 6 * 8192) {                 // 6 units * slot7 * 65536 halves
        int u = gid >> 13, i = gid & 8191;
        hbuf4[(size_t)(u * 8 + 7) * 8192 + i] = make_uint4(0, 0, 0, 0);
    }
    if (gid < 96) { zdone[gid] = 0; hdone[gid] = 0; }
}

// ---------------- main persistent pipeline kernel --------------------------------
// 6 units * 16 blocks (mtb 2 x colblk 8). Block tile = 64 rows x 64 cols.
struct PipeArgs {
    const h16* Wfrag;    // [6][32][32][64][8]
    const h16* zx0f;     // [2][T][nt32][mt8][64][4]
    const float* cb;     // [2][3][H]
    const float* lng;    // [3][H]
    const float* lnb;    // [3][H]
    h16* hbuf;           // [6][slot8][mt8][ks16][64][8]  (A-frag ring)
    h16* h2;             // [2][T][B][H]
    float* psum;         // [6][mtb2][64][8]
    float* psq;          // [6][mtb2][64][8]
    int* zdone;          // [96] = u*16 + widx
    int* hdone;          // [96]
};

__global__ __launch_bounds__(NTHR) void rnn_pipe(PipeArgs a)
{
    const int blk = blockIdx.x, tid = threadIdx.x;
    const int u = blk & 7;
    if (u >= 6) return;                    // 32 idle blocks exit
    const int widx = blk >> 3;             // 0..15
    const int colblk = widx & 7, mtb = widx >> 3;
    const int dir = u / 3, l = u % 3;
    const int wave = tid >> 6, lane = tid & 63;
    const int mt = mtb * 4 + wave;         // global m-tile 0..7
    const int r15 = lane & 15, quad = lane >> 4;

    const h16* __restrict__ Wfrag = a.Wfrag;
    const h16* __restrict__ zx0f  = a.zx0f;
    h16* __restrict__ hbuf = a.hbuf;
    float* __restrict__ psum = a.psum;
    float* __restrict__ psq  = a.psq;

    __shared__ h16 hl[64 * 68];            // h tile (rowpad 68)
    __shared__ float mrstd[128];           // [row][m,rstd]

    // per-thread constants for 4 n-tiles
    float cbv[4], gv[4], bv[4];
    #pragma unroll
    for (int nt = 0; nt < 4; ++nt) {
        int col = colblk * 64 + nt * 16 + r15;
        cbv[nt] = (l > 0) ? a.cb[(dir * 3 + l) * Hdim + col] : 0.f;
        gv[nt]  = a.lng[l * Hdim + col];
        bv[nt]  = a.lnb[l * Hdim + col];
    }
    const h16* wb = Wfrag + ((size_t)u * 32 * 32 + colblk * 4) * 512;

    for (int t = 0; t < Tdim; ++t) {
        // ---- pre-G wait: lower LN(t) done, own-unit LN(t-1) done, ring throttle ----
        for (;;) {
            int ok = 1;
            if (tid < 8) {
                if (l > 0) ok = (ld_flag(&a.hdone[(u - 1) * 16 + mtb * 8 + tid]) >= t + 1);
            } else if (tid < 16) {
                ok = (ld_flag(&a.hdone[u * 16 + mtb * 8 + (tid - 8)]) >= t);
            } else if (tid < 24) {
                if (l < 2 && t >= 8)
                    ok = (ld_flag(&a.hdone[(u + 1) * 16 + mtb * 8 + (tid - 16)]) >= t - 7);
            }
            if (__syncthreads_and(ok)) break;
            __builtin_amdgcn_s_sleep(1);
        }

        // ---- G: acc = zx0|0 + h_low@Wx + h_prev@Wh ----
        float4v acc[4];
        if (l == 0) {
            #pragma unroll
            for (int nt = 0; nt < 4; ++nt) {
                const h16* zp = zx0f +
                    ((((size_t)(dir * Tdim + t)) * 32 + (colblk * 4 + nt)) * 8 + mt) * 256 + lane * 4;
                acc[nt][0] = (float)zp[0]; acc[nt][1] = (float)zp[1];
                acc[nt][2] = (float)zp[2]; acc[nt][3] = (float)zp[3];
            }
        } else {
            #pragma unroll
            for (int nt = 0; nt < 4; ++nt) acc[nt] = (float4v){0.f, 0.f, 0.f, 0.f};
        }

        const h16* hlb = hbuf + (((size_t)(u - 1) * 8 + (t & 7)) * 8192 + (size_t)mt * 1024) * 8;
        const h16* hpb = hbuf + (((size_t)u * 8 + ((t + 7) & 7)) * 8192 + (size_t)mt * 1024) * 8;
        const int kbeg = (l == 0) ? 16 : 0;

        // software-pipelined A-frag loads (depth 8) over merged 32-ks loop
        half8 afq[8];
        #pragma unroll
        for (int i = 0; i < 8; ++i) {
            int ks2 = kbeg + i;
            afq[i] = (ks2 < 16) ? ld16c(&hlb[(ks2 * 64 + lane) * 8])
                                : ld16c(&hpb[((ks2 - 16) * 64 + lane) * 8]);
        }
        #pragma unroll
        for (int ks2 = kbeg; ks2 < 32; ++ks2) {
            half8 cur = afq[(ks2 - kbeg) & 7];
            int kn = ks2 + 8;
            if (kn < 32) {
                afq[(ks2 - kbeg) & 7] = (kn < 16) ? ld16c(&hlb[(kn * 64 + lane) * 8])
                                                  : ld16c(&hpb[((kn - 16) * 64 + lane) * 8]);
            }
            #pragma unroll
            for (int nt = 0; nt < 4; ++nt) {
                half8 bf = *(const half8*)&wb[(size_t)(ks2 * 32 + nt) * 512 + lane * 8];
                acc[nt] = __builtin_amdgcn_mfma_f32_16x16x32_f16(cur, bf, acc[nt], 0, 0, 0);
            }
        }

        // ---- epilogue: bias, per-row partial stats over own 64 cols ----
        float z[4][4];
        #pragma unroll
        for (int r = 0; r < 4; ++r) {
            float s = 0.f, q2 = 0.f;
            #pragma unroll
            for (int nt = 0; nt < 4; ++nt) {
                z[nt][r] = acc[nt][r] + cbv[nt];
                s += z[nt][r];
                q2 += z[nt][r] * z[nt][r];
            }
            s += __shfl_xor(s, 1);  q2 += __shfl_xor(q2, 1);
            s += __shfl_xor(s, 2);  q2 += __shfl_xor(q2, 2);
            s += __shfl_xor(s, 4);  q2 += __shfl_xor(q2, 4);
            s += __shfl_xor(s, 8);  q2 += __shfl_xor(q2, 8);
            if (r15 == 0) {
                int row = wave * 16 + quad * 4 + r;   // block-local row
                st_f32c(&psum[((u * 2 + mtb) * 64 + row) * 8 + colblk], s);
                st_f32c(&psq [((u * 2 + mtb) * 64 + row) * 8 + colblk], q2);
            }
        }
        __syncthreads();                    // drains vmcnt -> psum visible
        if (tid == 0) st_flag(&a.zdone[u * 16 + widx], t + 1);

        // ---- mid wait: 8 col-blocks of own (u, mtb) done with G(t) ----
        for (;;) {
            int ok = 1;
            if (tid < 8) ok = (ld_flag(&a.zdone[u * 16 + mtb * 8 + tid]) >= t + 1);
            if (__syncthreads_and(ok)) break;
            __builtin_amdgcn_s_sleep(1);
        }

        // ---- LN stats finalize (threads 0..63, one row each) ----
        if (tid < 64) {
            float sm = 0.f, sq = 0.f;
            #pragma unroll
            for (int c = 0; c < 8; ++c) {
                sm += ld_f32c(&psum[((u * 2 + mtb) * 64 + tid) * 8 + c]);
                sq += ld_f32c(&psq [((u * 2 + mtb) * 64 + tid) * 8 + c]);
            }
            float m = sm * (1.0f / Hdim);
            float var = sq * (1.0f / Hdim) - m * m;
            mrstd[2 * tid] = m;
            mrstd[2 * tid + 1] = rsqrtf(var + 1e-5f);
        }
        __syncthreads();

        // ---- LN + tanh -> LDS tile ----
        #pragma unroll
        for (int r = 0; r < 4; ++r) {
            int lrow = wave * 16 + quad * 4 + r;
            float m = mrstd[2 * lrow], rstd = mrstd[2 * lrow + 1];
            #pragma unroll
            for (int nt = 0; nt < 4; ++nt) {
                float hv = fast_tanh((z[nt][r] - m) * rstd * gv[nt] + bv[nt]);
                hl[lrow * 68 + nt * 16 + r15] = (h16)hv;
            }
        }
        __syncthreads();

        // ---- pack A-frags -> hbuf ring (sc-bypass), h2 plain (l==2) ----
        {
            #pragma unroll
            for (int ksl = 0; ksl < 2; ++ksl) {
                union { h16 h[8]; u64 u[2]; } o;
                const h16* src = &hl[(wave * 16 + r15) * 68 + ksl * 32 + quad * 8];
                #pragma unroll
                for (int j = 0; j < 8; ++j) o.h[j] = src[j];
                int ks = colblk * 2 + ksl;
                h16* dst = hbuf + (((size_t)u * 8 + (t & 7)) * 8192 +
                                   ((size_t)mt * 16 + ks) * 64 + lane) * 8;
                st16c(dst, o.u);
            }
            if (l == 2) {
                int row = tid >> 2, g2 = tid & 3;
                h16* d2 = a.h2 + (((size_t)dir * Tdim + t) * Bdim + mtb * 64 + row) * Hdim
                          + colblk * 64 + g2 * 16;
                uint4 v0, v1;
                const h16* src = &hl[row * 68 + g2 * 16];
                v0 = *(const uint4*)(src);
                v1 = *(const uint4*)(src + 8);
                *(uint4*)(d2) = v0;
                *(uint4*)(d2 + 8) = v1;
            }
        }
        __syncthreads();                    // drains vmcnt -> hbuf visible
        if (tid == 0) st_flag(&a.hdone[u * 16 + widx], t + 1);
    }
}

// ---------------- FC: logits = [h_l2r ; gather(h_r2l)] @ W_fc + b_fc -------------
__global__ __launch_bounds__(NTHR) void fc_kernel(
    const h16* __restrict__ h2, const int* __restrict__ pad,
    const float* __restrict__ Wfc, const float* __restrict__ bfc,
    float* __restrict__ out)
{
    __shared__ float sA[64 * 68];
    __shared__ float sB[64 * 48];
    const int blk = blockIdx.x, tid = threadIdx.x;
    const int b = blk >> 2;
    const int j0 = (blk & 3) * 64;
    const int p = pad[b];
    const int rg = tid >> 4;
    const int c0 = (tid & 15) * 3;
    float acc[4][3] = {};

    for (int k0 = 0; k0 < 2 * Hdim; k0 += 64) {
        {
            int rr = tid >> 2;
            int kp = (tid & 3) * 16;
            int j = j0 + rr;
            const h16* src;
            if (k0 < Hdim) {
                src = h2 + (((size_t)0 * Tdim + j) * Bdim + b) * Hdim + k0 + kp;
            } else {
                int idx = (j < p) ? (p - j - 1) : j;
                src = h2 + (((size_t)1 * Tdim + idx) * Bdim + b) * Hdim + (k0 - Hdim) + kp;
            }
            union { uint4 u4; h16 h[8]; } w0, w1;
            w0.u4 = *(const uint4*)src;
            w1.u4 = *(const uint4*)(src + 8);
            #pragma unroll
            for (int i = 0; i < 8; ++i) {
                sA[rr * 68 + kp + i]     = (float)w0.h[i];
                sA[rr * 68 + kp + 8 + i] = (float)w1.h[i];
            }
        }
        for (int e = tid; e < 64 * 48; e += NTHR) {
            int kk = e / 48, c = e - kk * 48;
            sB[e] = (c < NC) ? Wfc[(k0 + kk) * NC + c] : 0.f;
        }
        __syncthreads();
        for (int kk = 0; kk < 64; ++kk) {
            float b0 = sB[kk * 48 + c0 + 0];
            float b1 = sB[kk * 48 + c0 + 1];
            float b2 = sB[kk * 48 + c0 + 2];
            #pragma unroll
            for (int i = 0; i < 4; ++i) {
                float av = sA[(rg * 4 + i) * 68 + kk];
                acc[i][0] += av * b0; acc[i][1] += av * b1; acc[i][2] += av * b2;
            }
        }
        __syncthreads();
    }
    #pragma unroll
    for (int i = 0; i < 4; ++i) {
        int r = blk * 64 + rg * 4 + i;
        #pragma unroll
        for (int jj = 0; jj < 3; ++jj) {
            int c = c0 + jj;
            if (c < NC) out[r * NC + c] = acc[i][jj] + bfc[c];
        }
    }
}

extern "C" void kernel_launch(void* const* d_in, const int* in_sizes, int n_in,
                              void* d_out, int out_size, void* d_ws, size_t ws_size,
                              hipStream_t stream) {
    const float* x      = (const float*)d_in[0];
    const float* rx     = (const float*)d_in[1];
    const int*   pad    = (const int*)d_in[2];
    const float* Wemb   = (const float*)d_in[4];
    const float* bemb   = (const float*)d_in[5];
    const float* Wx_l2r = (const float*)d_in[6];
    const float* bx_l2r = (const float*)d_in[7];
    const float* Wh_l2r = (const float*)d_in[8];
    const float* bh_l2r = (const float*)d_in[9];
    const float* Wx_r2l = (const float*)d_in[10];
    const float* bx_r2l = (const float*)d_in[11];
    const float* Wh_r2l = (const float*)d_in[12];
    const float* bh_r2l = (const float*)d_in[13];
    const float* lng    = (const float*)d_in[14];
    const float* lnb    = (const float*)d_in[15];
    const float* Wfc    = (const float*)d_in[16];
    const float* bfc    = (const float*)d_in[17];

    char* base = (char*)d_ws;
    size_t off = 0;
    auto alloc = [&](size_t bytes) { char* p = base + off; off += (bytes + 255) & ~(size_t)255; return p; };
    h16*   zx0f  = (h16*)  alloc((size_t)2 * Tdim * 32 * 8 * 64 * 4 * 2);      // 67 MB
    h16*   h2    = (h16*)  alloc((size_t)2 * Tdim * Bdim * Hdim * 2);          // 67 MB
    h16*   Wfrag = (h16*)  alloc((size_t)6 * 32 * 32 * 64 * 8 * 2);            // 6.3 MB
    h16*   W0f   = (h16*)  alloc((size_t)2 * 32 * 10 * 64 * 8 * 2);            // 0.66 MB
    h16*   hbuf  = (h16*)  alloc((size_t)6 * 8 * 65536 * 2);                   // 6.3 MB
    float* psum  = (float*)alloc((size_t)6 * 2 * 64 * 8 * 4);
    float* psq   = (float*)alloc((size_t)6 * 2 * 64 * 8 * 4);
    float* W0    = (float*)alloc((size_t)2 * KXdim * Hdim * 4);                // 1.3 MB
    float* cb    = (float*)alloc((size_t)2 * 3 * Hdim * 4);
    int*   zdone = (int*)  alloc(96 * 4);
    int*   hdone = (int*)  alloc(96 * 4);

    prep1_kernel<<<(2 * KXdim * Hdim + 2 * 3 * Hdim) / NTHR, NTHR, 0, stream>>>(
        Wemb, bemb, Wx_l2r, bx_l2r, bh_l2r, Wx_r2l, bx_r2l, bh_r2l, W0, cb);

    pack_W_kernel<<<(6 * 32 * 32 * 64 * 8) / NTHR, NTHR, 0, stream>>>(
        W0, Wx_l2r, Wh_l2r, Wx_r2l, Wh_r2l, Wfrag);

    pack_W0f_kernel<<<(2 * 32 * 10 * 64 * 8) / NTHR, NTHR, 0, stream>>>(W0, W0f);

    zx0_kernel<<<1024, NTHR, 0, stream>>>(x, rx, W0f, cb, zx0f);

    zeroinit_kernel<<<(6 * 8192 + NTHR - 1) / NTHR, NTHR, 0, stream>>>(
        (uint4*)hbuf, zdone, hdone);

    PipeArgs a;
    a.Wfrag = Wfrag; a.zx0f = zx0f; a.cb = cb; a.lng = lng; a.lnb = lnb;
    a.hbuf = hbuf; a.h2 = h2; a.psum = psum; a.psq = psq;
    a.zdone = zdone; a.hdone = hdone;
    void* kargs[] = { &a };
    hipLaunchCooperativeKernel((void*)rnn_pipe, dim3(128), dim3(NTHR), kargs, 0, stream);

    fc_kernel<<<(Bdim * Tdim) / 64, NTHR, 0, stream>>>(h2, pad, Wfc, bfc, (float*)d_out);
}

// Round 6
// 3829.252 us; speedup vs baseline: 16.0532x; 16.0532x over previous
//
#include <hip/hip_runtime.h>

#define Bdim 128
#define Tdim 256
#define Hdim 512
#define INdim 300
#define KXdim 320
#define NC 45
#define NTHR 256

typedef _Float16 h16;
typedef __attribute__((ext_vector_type(8))) _Float16 half8;
typedef __attribute__((ext_vector_type(4))) float float4v;
typedef unsigned long long u64;

__device__ __forceinline__ float fast_tanh(float v) {
    float e = __expf(2.0f * v);
    return 1.0f - 2.0f / (e + 1.0f);
}

// ---- coherence-point (sc0 sc1) access helpers: relaxed agent-scope atomics ----
__device__ __forceinline__ int ld_flag(const int* p) {
    return __hip_atomic_load((int*)p, __ATOMIC_RELAXED, __HIP_MEMORY_SCOPE_AGENT);
}
__device__ __forceinline__ void st_flag(int* p, int v) {
    __hip_atomic_store(p, v, __ATOMIC_RELAXED, __HIP_MEMORY_SCOPE_AGENT);
}
__device__ __forceinline__ float ld_f32c(const float* p) {
    return __hip_atomic_load((float*)p, __ATOMIC_RELAXED, __HIP_MEMORY_SCOPE_AGENT);
}
__device__ __forceinline__ void st_f32c(float* p, float v) {
    __hip_atomic_store(p, v, __ATOMIC_RELAXED, __HIP_MEMORY_SCOPE_AGENT);
}
// 16B fragment load as two b64 relaxed agent atomics (R4-proven)
__device__ __forceinline__ half8 ld16c(const h16* p) {
    union { u64 u[2]; half8 h; } r;
    const u64* q = (const u64*)p;
    r.u[0] = __hip_atomic_load((u64*)(q + 0), __ATOMIC_RELAXED, __HIP_MEMORY_SCOPE_AGENT);
    r.u[1] = __hip_atomic_load((u64*)(q + 1), __ATOMIC_RELAXED, __HIP_MEMORY_SCOPE_AGENT);
    return r.h;
}
__device__ __forceinline__ void st8c(h16* p, const uint* u) {
    uint* q = (uint*)p;
    __hip_atomic_store(q + 0, u[0], __ATOMIC_RELAXED, __HIP_MEMORY_SCOPE_AGENT);
    __hip_atomic_store(q + 1, u[1], __ATOMIC_RELAXED, __HIP_MEMORY_SCOPE_AGENT);
    __hip_atomic_store(q + 2, u[2], __ATOMIC_RELAXED, __HIP_MEMORY_SCOPE_AGENT);
    __hip_atomic_store(q + 3, u[3], __ATOMIC_RELAXED, __HIP_MEMORY_SCOPE_AGENT);
}

// ---------------- prep1: W0 = Wemb @ Wx0 (fp32), cb fused biases ----------------
__global__ __launch_bounds__(NTHR) void prep1_kernel(
    const float* Wemb, const float* bemb,
    const float* Wx_l2r, const float* bx_l2r, const float* bh_l2r,
    const float* Wx_r2l, const float* bx_r2l, const float* bh_r2l,
    float* W0, float* cb)
{
    int gid = blockIdx.x * NTHR + threadIdx.x;
    const int nW0 = 2 * KXdim * Hdim;
    if (gid < nW0) {
        int dir = gid / (KXdim * Hdim);
        int rem = gid % (KXdim * Hdim);
        int i = rem / Hdim, h = rem % Hdim;
        const float* Wx = dir ? Wx_r2l : Wx_l2r;
        float s = 0.f;
        if (i < INdim) {
            for (int k = 0; k < Hdim; ++k)
                s += Wemb[i * Hdim + k] * Wx[k * Hdim + h];
        }
        W0[gid] = s;
    } else {
        int idx = gid - nW0;
        if (idx < 2 * 3 * Hdim) {
            int dir = idx / (3 * Hdim);
            int l = (idx / Hdim) % 3;
            int h = idx % Hdim;
            const float* Wx = dir ? Wx_r2l : Wx_l2r;
            const float* bx = dir ? bx_r2l : bx_l2r;
            const float* bh = dir ? bh_r2l : bh_l2r;
            float s = bx[l * Hdim + h] + bh[l * Hdim + h];
            if (l == 0) {
                for (int k = 0; k < Hdim; ++k)
                    s += bemb[k] * Wx[k * Hdim + h];
            }
            cb[idx] = s;
        }
    }
}

// ---------------- pack_W: fp16 B-frag layout [u][cs16][ks32][nt2][lane64][j8] ----
__global__ __launch_bounds__(NTHR) void pack_W_kernel(
    const float* W0,
    const float* Wx_l2r, const float* Wh_l2r,
    const float* Wx_r2l, const float* Wh_r2l,
    h16* Wfrag)
{
    int e = blockIdx.x * NTHR + threadIdx.x;
    if (e >= 6 * 16 * 32 * 2 * 64 * 8) return;
    int j    = e & 7;
    int lane = (e >> 3) & 63;
    int nt   = (e >> 9) & 1;
    int ks   = (e >> 10) & 31;
    int cs   = (e >> 15) & 15;
    int u    = e >> 19;
    int dir = u / 3, l = u % 3;
    int n  = cs * 32 + nt * 16 + (lane & 15);
    int kk = ks * 32 + ((lane >> 4) * 8) + j;
    float v;
    if (kk < 512) {
        if (l == 0) {
            v = (kk < KXdim) ? W0[(dir * KXdim + kk) * Hdim + n] : 0.f;
        } else {
            const float* Wx = dir ? Wx_r2l : Wx_l2r;
            v = Wx[(l * Hdim + kk) * Hdim + n];
        }
    } else {
        const float* Wh = dir ? Wh_r2l : Wh_l2r;
        v = Wh[(l * Hdim + (kk - 512)) * Hdim + n];
    }
    Wfrag[e] = (h16)v;
}

// ---------------- pack_W0f: fp16 B-frags of W0 for zx0 kernel --------------------
__global__ __launch_bounds__(NTHR) void pack_W0f_kernel(const float* W0, h16* W0f)
{
    int e = blockIdx.x * NTHR + threadIdx.x;
    if (e >= 2 * 32 * 10 * 64 * 8) return;
    int j    = e & 7;
    int lane = (e >> 3) & 63;
    int rest = e >> 9;
    int ks   = rest % 10;
    rest /= 10;
    int nt   = rest & 31;
    int dir  = rest >> 5;
    int k = ks * 32 + ((lane >> 4) * 8) + j;
    int n = nt * 16 + (lane & 15);
    W0f[e] = (h16)W0[(dir * KXdim + k) * Hdim + n];
}

// ---------------- zx0: zx0f[dir][t][nt32][mt8][lane64][reg4] fp16 ----------------
__global__ __launch_bounds__(NTHR) void zx0_kernel(
    const float* __restrict__ x0, const float* __restrict__ x1,
    const h16* __restrict__ W0f, const float* __restrict__ cb,
    h16* __restrict__ zx0f)
{
    int bx = blockIdx.x;
    int t = bx & 255, mh = (bx >> 8) & 1, dir = bx >> 9;
    const int tid = threadIdx.x;
    __shared__ h16 xl[64 * 328];
    const float* xs = dir ? x1 : x0;
    for (int i = tid; i < 64 * 328; i += NTHR) {
        int r = i / 328, k = i - r * 328;
        int b = mh * 64 + r;
        float v = (k < INdim) ? xs[(b * Tdim + t) * INdim + k] : 0.f;
        xl[i] = (h16)v;
    }
    __syncthreads();
    int wave = tid >> 6, lane = tid & 63;
    int r15 = lane & 15, q = lane >> 4;
    for (int nt = 0; nt < 32; ++nt) {
        float4v acc = {0.f, 0.f, 0.f, 0.f};
        #pragma unroll
        for (int ks = 0; ks < 10; ++ks) {
            half8 af = *(const half8*)&xl[(wave * 16 + r15) * 328 + ks * 32 + q * 8];
            half8 bf = *(const half8*)&W0f[(((dir * 32 + nt) * 10 + ks) * 64 + lane) * 8];
            acc = __builtin_amdgcn_mfma_f32_16x16x32_f16(af, bf, acc, 0, 0, 0);
        }
        int col = nt * 16 + r15;
        float cbv = cb[(dir * 3 + 0) * Hdim + col];
        union { h16 h[4]; uint2 u2; } o;
        #pragma unroll
        for (int r = 0; r < 4; ++r) o.h[r] = (h16)(acc[r] + cbv);
        h16* dst = zx0f + (((( (size_t)dir * Tdim + t) * 32 + nt) * 8 + (mh * 4 + wave)) * 64 + lane) * 4;
        *(uint2*)dst = o.u2;
    }
}

// ---------------- zeroinit: hbuf ring slot 3 + flags -----------------------------
__global__ __launch_bounds__(NTHR) void zeroinit_kernel(uint4* hfrag4, int* zdone, int* hdone)
{
    int gid = blockIdx.x * NTHR + threadIdx.x;
    if (gid < 6 * 8192) {
        int u = gid >> 13, i = gid & 8191;
        hfrag4[(size_t)(u * 4 + 3) * 8192 + i] = make_uint4(0, 0, 0, 0);
    }
    if (gid < 6 * 32) { zdone[gid] = 0; hdone[gid] = 0; }
}

// ---------------- main persistent pipeline kernel --------------------------------
// 6 units * 32 blocks (mtblk2 x cs16). Block tile = 64 rows x 32 cols. (R3 shape)
struct PipeArgs {
    const h16* Wfrag;    // [6][cs16][ks32][nt2][64][8]
    const h16* zx0f;     // [2][T][nt32][mt8][64][4]
    const float* cb;     // [2][3][H]
    const float* lng;    // [3][H]
    const float* lnb;    // [3][H]
    h16* hfrag;          // [6][slot4][ks16][mt8][64][8]  (A-frag ring)
    h16* h2;             // [2][T][B][H]
    float* psum;         // [6][B][16]
    float* psq;          // [6][B][16]
    int* zdone;          // [6][32]
    int* hdone;          // [6][32]
};

__global__ __launch_bounds__(NTHR, 1) void rnn_pipe(PipeArgs a)
{
    const int blk = blockIdx.x, tid = threadIdx.x;
    const int u = blk & 7;
    if (u >= 6) return;                    // 64 idle blocks exit
    const int widx = blk >> 3;             // 0..31
    const int mtblk = widx & 1, cs = widx >> 1;
    const int dir = u / 3, l = u % 3;
    const int wave = tid >> 6, lane = tid & 63;
    const int gmt = mtblk * 4 + wave;      // m-tile 0..7
    const int r15 = lane & 15, quad = lane >> 4;

    h16* __restrict__ hbuf = a.hfrag;
    float* __restrict__ psum = a.psum;
    float* __restrict__ psq  = a.psq;

    __shared__ h16 wlds[16384];            // 32 KB Wh frags [ks16][nt2][64][8]
    __shared__ float lds_ps[64 * 16];      // 4 KB
    __shared__ float lds_pq[64 * 16];      // 4 KB
    __shared__ h16 lds_z[64 * 32];         // 4 KB

    {   // stage Wh half (global ks 16..31) into LDS
        const h16* src = a.Wfrag + (size_t)(u * 16 + cs) * 32768 + 16384;
        for (int i = tid * 8; i < 16384; i += NTHR * 8)
            *(uint4*)&wlds[i] = *(const uint4*)&src[i];
    }
    __syncthreads();

    const h16* wxg = a.Wfrag + (size_t)(u * 16 + cs) * 32768;   // Wx frags (L2 plain)
    const int colbase = cs * 32 + r15;
    const float cb0v = (l > 0) ? a.cb[(dir * 3 + l) * Hdim + colbase] : 0.f;
    const float cb1v = (l > 0) ? a.cb[(dir * 3 + l) * Hdim + colbase + 16] : 0.f;
    const float g0  = a.lng[l * Hdim + colbase];
    const float g1  = a.lng[l * Hdim + colbase + 16];
    const float bb0 = a.lnb[l * Hdim + colbase];
    const float bb1 = a.lnb[l * Hdim + colbase + 16];

    for (int t = 0; t < Tdim; ++t) {
        // ---- pre-G wait: own LN(t-1), lower LN(t), ring throttle ----
        for (;;) {
            int ok = 1;
            if (tid < 32) {
                ok = (ld_flag(&a.hdone[u * 32 + tid]) >= t);
            } else if (tid >= 64 && tid < 96) {
                if (l > 0) ok = (ld_flag(&a.hdone[(u - 1) * 32 + (tid - 64)]) >= t + 1);
            } else if (tid >= 128 && tid < 160) {
                if (l < 2 && t >= 4) ok = (ld_flag(&a.zdone[(u + 1) * 32 + (tid - 128)]) >= t - 3);
            }
            if (__syncthreads_and(ok)) break;
            __builtin_amdgcn_s_sleep(2);
        }

        // ---- G phase: batched A-frag loads (overlapped IF$ RTTs), then MFMA ----
        float4v acc0, acc1;
        const h16* basePrev = hbuf + (size_t)(u * 4 + ((t + 3) & 3)) * 65536;
        if (l == 0) {
            half8 afP[16];
            #pragma unroll
            for (int k = 0; k < 16; ++k)
                afP[k] = ld16c(&basePrev[((k * 8 + gmt) * 64 + lane) * 8]);
            const h16* zp = a.zx0f +
                (((((size_t)dir * Tdim + t) * 32 + cs * 2) * 8 + gmt) * 64 + lane) * 4;
            acc0[0] = (float)zp[0]; acc0[1] = (float)zp[1];
            acc0[2] = (float)zp[2]; acc0[3] = (float)zp[3];
            const h16* zp1 = zp + 2048;
            acc1[0] = (float)zp1[0]; acc1[1] = (float)zp1[1];
            acc1[2] = (float)zp1[2]; acc1[3] = (float)zp1[3];
            #pragma unroll
            for (int ks = 0; ks < 16; ++ks) {
                half8 bh0 = *(const half8*)&wlds[((ks * 2 + 0) * 64 + lane) * 8];
                half8 bh1 = *(const half8*)&wlds[((ks * 2 + 1) * 64 + lane) * 8];
                acc0 = __builtin_amdgcn_mfma_f32_16x16x32_f16(afP[ks], bh0, acc0, 0, 0, 0);
                acc1 = __builtin_amdgcn_mfma_f32_16x16x32_f16(afP[ks], bh1, acc1, 0, 0, 0);
            }
        } else {
            const h16* baseLow = hbuf + (size_t)((u - 1) * 4 + (t & 3)) * 65536;
            half8 afL[16], afP[16];
            #pragma unroll
            for (int k = 0; k < 16; ++k)
                afL[k] = ld16c(&baseLow[((k * 8 + gmt) * 64 + lane) * 8]);
            #pragma unroll
            for (int k = 0; k < 16; ++k)
                afP[k] = ld16c(&basePrev[((k * 8 + gmt) * 64 + lane) * 8]);
            acc0 = (float4v){0.f, 0.f, 0.f, 0.f};
            acc1 = (float4v){0.f, 0.f, 0.f, 0.f};
            #pragma unroll
            for (int ks = 0; ks < 16; ++ks) {
                half8 bx0 = *(const half8*)&wxg[((ks * 2 + 0) * 64 + lane) * 8];
                half8 bx1 = *(const half8*)&wxg[((ks * 2 + 1) * 64 + lane) * 8];
                half8 bh0 = *(const half8*)&wlds[((ks * 2 + 0) * 64 + lane) * 8];
                half8 bh1 = *(const half8*)&wlds[((ks * 2 + 1) * 64 + lane) * 8];
                acc0 = __builtin_amdgcn_mfma_f32_16x16x32_f16(afL[ks], bx0, acc0, 0, 0, 0);
                acc1 = __builtin_amdgcn_mfma_f32_16x16x32_f16(afL[ks], bx1, acc1, 0, 0, 0);
                acc0 = __builtin_amdgcn_mfma_f32_16x16x32_f16(afP[ks], bh0, acc0, 0, 0, 0);
                acc1 = __builtin_amdgcn_mfma_f32_16x16x32_f16(afP[ks], bh1, acc1, 0, 0, 0);
            }
        }

        // ---- epilogue: bias, z in regs, per-row partial stats -> psum ----
        float z0[4], z1[4];
        #pragma unroll
        for (int r = 0; r < 4; ++r) {
            z0[r] = acc0[r] + cb0v;
            z1[r] = acc1[r] + cb1v;
            float s = z0[r] + z1[r];
            float q2 = z0[r] * z0[r] + z1[r] * z1[r];
            s += __shfl_xor(s, 1);  q2 += __shfl_xor(q2, 1);
            s += __shfl_xor(s, 2);  q2 += __shfl_xor(q2, 2);
            s += __shfl_xor(s, 4);  q2 += __shfl_xor(q2, 4);
            s += __shfl_xor(s, 8);  q2 += __shfl_xor(q2, 8);
            if (r15 == 0) {
                int b = mtblk * 64 + wave * 16 + quad * 4 + r;
                st_f32c(&psum[(u * Bdim + b) * 16 + cs], s);
                st_f32c(&psq [(u * Bdim + b) * 16 + cs], q2);
            }
        }
        __syncthreads();                    // drains vmcnt -> psum visible
        if (tid == 0) st_flag(&a.zdone[u * 32 + widx], t + 1);

        // ---- mid wait: all 32 unit blocks' psum for step t ----
        for (;;) {
            int ok = 1;
            if (tid < 32) ok = (ld_flag(&a.zdone[u * 32 + tid]) >= t + 1);
            if (__syncthreads_and(ok)) break;
            __builtin_amdgcn_s_sleep(2);
        }

        // ---- LN stats: stage psum/psq rows into LDS ----
        {
            int flat = tid * 4;
            int rl = flat >> 4, c = flat & 15;
            int b = mtblk * 64 + rl;
            #pragma unroll
            for (int j = 0; j < 4; ++j) {
                lds_ps[rl * 16 + c + j] = ld_f32c(&psum[(u * Bdim + b) * 16 + c + j]);
                lds_pq[rl * 16 + c + j] = ld_f32c(&psq [(u * Bdim + b) * 16 + c + j]);
            }
        }
        __syncthreads();
        // ---- LN + tanh -> LDS tile ----
        #pragma unroll
        for (int r = 0; r < 4; ++r) {
            int lrow = wave * 16 + quad * 4 + r;
            float sm = 0.f, sq = 0.f;
            #pragma unroll
            for (int c = 0; c < 16; ++c) { sm += lds_ps[lrow * 16 + c]; sq += lds_pq[lrow * 16 + c]; }
            float m = sm * (1.0f / Hdim);
            float var = sq * (1.0f / Hdim) - m * m;
            float rstd = rsqrtf(var + 1e-5f);
            lds_z[lrow * 32 + r15]      = (h16)fast_tanh((z0[r] - m) * rstd * g0 + bb0);
            lds_z[lrow * 32 + r15 + 16] = (h16)fast_tanh((z1[r] - m) * rstd * g1 + bb1);
        }
        __syncthreads();

        // ---- pack A-frags -> hfrag ring (1 frag/thread), h2 plain (l==2) ----
        {
            int b_l = tid >> 2, c0 = (tid & 3) * 8;
            union { h16 h[8]; uint u4[4]; uint4 v; } o;
            const h16* src = &lds_z[b_l * 32 + c0];
            #pragma unroll
            for (int j = 0; j < 8; ++j) o.h[j] = src[j];
            int mt = mtblk * 4 + (b_l >> 4);
            int lane2 = (b_l & 15) | ((tid & 3) << 4);
            h16* dst = hbuf + (size_t)(u * 4 + (t & 3)) * 65536 +
                       ((size_t)((cs * 8 + mt) * 64 + lane2)) * 8;
            st8c(dst, o.u4);
            if (l == 2) {
                h16* d2 = a.h2 + (((size_t)dir * Tdim + t) * Bdim + mtblk * 64 + b_l) * Hdim
                          + cs * 32 + c0;
                *(uint4*)d2 = o.v;
            }
        }
        __syncthreads();                    // drains vmcnt -> hfrag visible
        if (tid == 0) st_flag(&a.hdone[u * 32 + widx], t + 1);
    }
}

// ---------------- FC: logits = [h_l2r ; gather(h_r2l)] @ W_fc + b_fc -------------
__global__ __launch_bounds__(NTHR) void fc_kernel(
    const h16* __restrict__ h2, const int* __restrict__ pad,
    const float* __restrict__ Wfc, const float* __restrict__ bfc,
    float* __restrict__ out)
{
    __shared__ float sA[64 * 68];
    __shared__ float sB[64 * 48];
    const int blk = blockIdx.x, tid = threadIdx.x;
    const int b = blk >> 2;
    const int j0 = (blk & 3) * 64;
    const int p = pad[b];
    const int rg = tid >> 4;
    const int c0 = (tid & 15) * 3;
    float acc[4][3] = {};

    for (int k0 = 0; k0 < 2 * Hdim; k0 += 64) {
        {
            int rr = tid >> 2;
            int kp = (tid & 3) * 16;
            int j = j0 + rr;
            const h16* src;
            if (k0 < Hdim) {
                src = h2 + (((size_t)0 * Tdim + j) * Bdim + b) * Hdim + k0 + kp;
            } else {
                int idx = (j < p) ? (p - j - 1) : j;
                src = h2 + (((size_t)1 * Tdim + idx) * Bdim + b) * Hdim + (k0 - Hdim) + kp;
            }
            union { uint4 u4; h16 h[8]; } w0, w1;
            w0.u4 = *(const uint4*)src;
            w1.u4 = *(const uint4*)(src + 8);
            #pragma unroll
            for (int i = 0; i < 8; ++i) {
                sA[rr * 68 + kp + i]     = (float)w0.h[i];
                sA[rr * 68 + kp + 8 + i] = (float)w1.h[i];
            }
        }
        for (int e = tid; e < 64 * 48; e += NTHR) {
            int kk = e / 48, c = e - kk * 48;
            sB[e] = (c < NC) ? Wfc[(k0 + kk) * NC + c] : 0.f;
        }
        __syncthreads();
        for (int kk = 0; kk < 64; ++kk) {
            float b0 = sB[kk * 48 + c0 + 0];
            float b1 = sB[kk * 48 + c0 + 1];
            float b2 = sB[kk * 48 + c0 + 2];
            #pragma unroll
            for (int i = 0; i < 4; ++i) {
                float av = sA[(rg * 4 + i) * 68 + kk];
                acc[i][0] += av * b0; acc[i][1] += av * b1; acc[i][2] += av * b2;
            }
        }
        __syncthreads();
    }
    #pragma unroll
    for (int i = 0; i < 4; ++i) {
        int r = blk * 64 + rg * 4 + i;
        #pragma unroll
        for (int jj = 0; jj < 3; ++jj) {
            int c = c0 + jj;
            if (c < NC) out[r * NC + c] = acc[i][jj] + bfc[c];
        }
    }
}

extern "C" void kernel_launch(void* const* d_in, const int* in_sizes, int n_in,
                              void* d_out, int out_size, void* d_ws, size_t ws_size,
                              hipStream_t stream) {
    const float* x      = (const float*)d_in[0];
    const float* rx     = (const float*)d_in[1];
    const int*   pad    = (const int*)d_in[2];
    const float* Wemb   = (const float*)d_in[4];
    const float* bemb   = (const float*)d_in[5];
    const float* Wx_l2r = (const float*)d_in[6];
    const float* bx_l2r = (const float*)d_in[7];
    const float* Wh_l2r = (const float*)d_in[8];
    const float* bh_l2r = (const float*)d_in[9];
    const float* Wx_r2l = (const float*)d_in[10];
    const float* bx_r2l = (const float*)d_in[11];
    const float* Wh_r2l = (const float*)d_in[12];
    const float* bh_r2l = (const float*)d_in[13];
    const float* lng    = (const float*)d_in[14];
    const float* lnb    = (const float*)d_in[15];
    const float* Wfc    = (const float*)d_in[16];
    const float* bfc    = (const float*)d_in[17];

    char* base = (char*)d_ws;
    size_t off = 0;
    auto alloc = [&](size_t bytes) { char* p = base + off; off += (bytes + 255) & ~(size_t)255; return p; };
    h16*   zx0f  = (h16*)  alloc((size_t)2 * Tdim * 32 * 8 * 64 * 4 * 2);      // 67 MB
    h16*   h2    = (h16*)  alloc((size_t)2 * Tdim * Bdim * Hdim * 2);          // 67 MB
    h16*   Wfrag = (h16*)  alloc((size_t)6 * 16 * 32768 * 2);                  // 6.3 MB
    h16*   W0f   = (h16*)  alloc((size_t)2 * 32 * 10 * 64 * 8 * 2);            // 0.66 MB
    h16*   hfrag = (h16*)  alloc((size_t)6 * 4 * 65536 * 2);                   // 3.1 MB
    float* psum  = (float*)alloc((size_t)6 * Bdim * 16 * 4);
    float* psq   = (float*)alloc((size_t)6 * Bdim * 16 * 4);
    float* W0    = (float*)alloc((size_t)2 * KXdim * Hdim * 4);
    float* cb    = (float*)alloc((size_t)2 * 3 * Hdim * 4);
    int*   zdone = (int*)  alloc(192 * 4);
    int*   hdone = (int*)  alloc(192 * 4);

    prep1_kernel<<<(2 * KXdim * Hdim + 2 * 3 * Hdim) / NTHR, NTHR, 0, stream>>>(
        Wemb, bemb, Wx_l2r, bx_l2r, bh_l2r, Wx_r2l, bx_r2l, bh_r2l, W0, cb);

    pack_W_kernel<<<(6 * 16 * 32 * 2 * 64 * 8) / NTHR, NTHR, 0, stream>>>(
        W0, Wx_l2r, Wh_l2r, Wx_r2l, Wh_r2l, Wfrag);

    pack_W0f_kernel<<<(2 * 32 * 10 * 64 * 8) / NTHR, NTHR, 0, stream>>>(W0, W0f);

    zx0_kernel<<<1024, NTHR, 0, stream>>>(x, rx, W0f, cb, zx0f);

    zeroinit_kernel<<<(6 * 8192 + NTHR - 1) / NTHR, NTHR, 0, stream>>>(
        (uint4*)hfrag, zdone, hdone);

    PipeArgs a;
    a.Wfrag = Wfrag; a.zx0f = zx0f; a.cb = cb; a.lng = lng; a.lnb = lnb;
    a.hfrag = hfrag; a.h2 = h2; a.psum = psum; a.psq = psq;
    a.zdone = zdone; a.hdone = hdone;
    void* kargs[] = { &a };
    hipLaunchCooperativeKernel((void*)rnn_pipe, dim3(256), dim3(NTHR), kargs, 0, stream);

    fc_kernel<<<(Bdim * Tdim) / 64, NTHR, 0, stream>>>(h2, pad, Wfc, bfc, (float*)d_out);
}